// Round 6
// baseline (3916.264 us; speedup 1.0000x reference)
//
#include <hip/hip_runtime.h>
#include <stdint.h>

// ====== variant switches for XLA:CPU transcendental reconstruction ======
// (verified bit-exact in round 1 — DO NOT change the math)
#define XLA_LOG_TAIL_A 1
#define XLA_USE_FMA    0

#if XLA_USE_FMA
#define MADD(a,b,c) __builtin_fmaf((a),(b),(c))
#else
#define MADD(a,b,c) ((a)*(b)+(c))
#endif

#define N_NEUR 2048
#define HALF_N 1024

// raw barrier: LDS-only ordering (no vmcnt drain — stores stay in flight)
#define LDS_BARRIER()                                            \
  do {                                                           \
    __asm__ __volatile__("s_waitcnt lgkmcnt(0)" ::: "memory");   \
    __builtin_amdgcn_s_barrier();                                \
    __asm__ __volatile__("" ::: "memory");                       \
  } while (0)

// ---------------- threefry2x32 (exact JAX primitive) ----------------
__device__ __forceinline__ uint32_t rotl32(uint32_t x, int r) {
  return (x << r) | (x >> (32 - r));
}

__device__ __forceinline__ void tf2x32(uint32_t k0, uint32_t k1,
                                       uint32_t& x0, uint32_t& x1) {
  const uint32_t k2 = k0 ^ k1 ^ 0x1BD11BDAu;
  x0 += k0; x1 += k1;
#define TF_R(r) { x0 += x1; x1 = rotl32(x1, r); x1 ^= x0; }
  TF_R(13) TF_R(15) TF_R(26) TF_R(6)
  x0 += k1; x1 += k2 + 1u;
  TF_R(17) TF_R(29) TF_R(16) TF_R(24)
  x0 += k2; x1 += k0 + 2u;
  TF_R(13) TF_R(15) TF_R(26) TF_R(6)
  x0 += k0; x1 += k1 + 3u;
  TF_R(17) TF_R(29) TF_R(16) TF_R(24)
  x0 += k1; x1 += k2 + 4u;
  TF_R(13) TF_R(15) TF_R(26) TF_R(6)
  x0 += k2; x1 += k0 + 5u;
#undef TF_R
}

__device__ __forceinline__ float u01_from_bits(uint32_t bits) {
#pragma clang fp contract(off)
  float f = __uint_as_float((bits >> 9) | 0x3f800000u);
  return f - 1.0f;
}

// ---------------- XLA:CPU GenerateVF32Log (Cephes, Estrin poly) ----------------
__device__ __forceinline__ float xla_log(float xin) {
#pragma clang fp contract(off)
  float t0 = fmaxf(xin, __uint_as_float(0x00800000u));
  uint32_t bits = __float_as_uint(t0);
  int em = (int)(bits >> 23) - 127;
  t0 = __uint_as_float((bits & 0x807fffffu) | 0x3f000000u);
  float e = 1.0f + (float)em;
  const bool mlt = t0 < (float)0.707106781186547524;
  float tmp1 = mlt ? t0 : 0.0f;
  t0 = t0 - 1.0f;
  e = e - (mlt ? 1.0f : 0.0f);
  t0 = t0 + tmp1;
  float x2 = t0 * t0;
  float x3 = x2 * t0;
  float y  = MADD(t0, (float)7.0376836292E-2, (float)-1.1514610310E-1);
  float ya = MADD(t0, (float)-1.2420140846E-1, (float)1.4249322787E-1);
  float yb = MADD(t0, (float)2.0000714765E-1, (float)-2.4999993993E-1);
  y  = MADD(y,  t0, (float)1.1676998740E-1);
  ya = MADD(ya, t0, (float)-1.6668057665E-1);
  yb = MADD(yb, t0, (float)3.3333331174E-1);
  y  = MADD(y, x3, ya);
  y  = MADD(y, x3, yb);
  y  = y * x3;
  float ey1 = e * (float)-2.12194440e-4;
  float hx2 = x2 * 0.5f;
  y = y + ey1;
  t0 = t0 - hx2;
  float ey2 = e * (float)0.693359375;
#if XLA_LOG_TAIL_A
  t0 = t0 + y;
  t0 = t0 + ey2;
#else
  t0 = t0 + ey2;
  t0 = t0 + y;
#endif
  if (xin == 0.0f) return -__builtin_inff();
  return t0;
}

// ---------------- XLA:CPU GenerateVF32Exp (old Cephes structure) ----------------
__device__ __forceinline__ float xla_exp(float xin) {
#pragma clang fp contract(off)
  float x = fmaxf(xin, (float)-88.3762626647949);
  x = fminf(x, (float)88.3762626647950);
  float fx = floorf(MADD(x, (float)1.44269504088896341, 0.5f));
  float tmp = (float)0.693359375 * fx;
  float z = (float)-2.12194440e-4 * fx;
  x = x - tmp;
  x = x - z;
  z = x * x;
  float y = MADD(x, (float)1.9875691500E-4, (float)1.3981999507E-3);
  y = MADD(y, x, (float)8.3334519073E-3);
  y = MADD(y, x, (float)4.1665795894E-2);
  y = MADD(y, x, (float)1.6666665459E-1);
  y = MADD(y, x, (float)5.0000001201E-1);
  y = MADD(y, z, x);
  y = 1.0f + y;
  int n = (int)fx;
  float p2n = __uint_as_float((uint32_t)(n + 127) << 23);
  return fmaxf(y * p2n, xin);
}

__device__ __forceinline__ float xla_log1p(float x) {
#pragma clang fp contract(off)
  float fl = xla_log(x + 1.0f);
  float fs = ((-0.5f * x) + 1.0f) * x;
  return (fabsf(x) < (float)1e-4) ? fs : fl;
}

// jax.nn.softplus(v) = max(v,0) + log1p(exp(-|v|))
__device__ __forceinline__ float softplus_xla(float v) {
#pragma clang fp contract(off)
  // exact shortcut: for v>=16, exp(-v)<=1.13e-7 < ulp(v)/2 -> sum rounds to v
  if (v >= 16.0f) return v;
  float a = fabsf(v);
  float ex = xla_exp(-a);
  float lp = xla_log1p(ex);
  return fmaxf(v, 0.0f) + lp;
}

// ---------------- init: tevents/yevents = +inf, event_types = 0 ----------------
__global__ void snn_init(float* __restrict__ out, size_t inf_base,
                         size_t inf_cnt, size_t zero_cnt) {
  size_t i = (size_t)blockIdx.x * blockDim.x + threadIdx.x;
  size_t stride = (size_t)gridDim.x * blockDim.x;
  size_t total = inf_cnt + zero_cnt;
  for (size_t k = i; k < total; k += stride) {
    out[inf_base + k] = (k < inf_cnt) ? __builtin_inff() : 0.0f;
  }
}

// ---------------- precompute s_reset[step][j] = log(u)-alpha into sres ---------
__global__ __launch_bounds__(1024)
void snn_pre(const int* __restrict__ seedp, float* __restrict__ sres) {
#pragma clang fp contract(off)
  const int step = blockIdx.x;       // 0..T-2
  const int t = threadIdx.x;
  uint32_t seed = (uint32_t)seedp[0];
  uint32_t a0 = 0u, a1 = 2u; tf2x32(0u, seed, a0, a1);
  uint32_t b0 = 1u, b1 = 3u; tf2x32(0u, seed, b0, b1);
  uint32_t f0 = 0u, f1 = (uint32_t)step; tf2x32(a1, b1, f0, f1);
  uint32_t d0 = (uint32_t)t, d1 = (uint32_t)(t + HALF_N);
  tf2x32(f0, f1, d0, d1);
  float srA = xla_log(u01_from_bits(d0)) - 0.01f;
  float srB = xla_log(u01_from_bits(d1)) - 0.01f;
  sres[(size_t)step * N_NEUR + t] = srA;
  sres[(size_t)step * N_NEUR + HALF_N + t] = srB;
}

// ------- the sequential scan: 1 block, 1024 threads, 2 contiguous neurons -----
// One raw LDS barrier per step (no vmcnt drain); ds_min reduce; wave-uniform
// softplus shortcut; ts/sres register-pipelined.
template <bool USE_SRES>
__global__ __launch_bounds__(1024, 1)
void snn_sim(const float* __restrict__ ts, const float* __restrict__ v0,
             const float* __restrict__ i0, const float* __restrict__ ic,
             const float* __restrict__ w, const float* __restrict__ mu,
             const int* __restrict__ seedp, const float* __restrict__ sres,
             float* __restrict__ out, int T, int MS) {
#pragma clang fp contract(off)
  const int tid = threadIdx.x;
  const int nb = tid * 2;               // neurons nb, nb+1
  const int lane = tid & 63;

  float* ys   = out;                                     // [T][N][3]
  float* tev  = out + (size_t)T * N_NEUR * 3;            // [MS]
  float* yev  = tev + (size_t)MS;                        // [MS][N][3]
  float* etv  = yev + (size_t)MS * N_NEUR * 3;           // [MS][N]
  float* nspp = etv + (size_t)MS * N_NEUR;               // [1]

  // keys: key=(0,seed); split -> k_init (first cipher words), k_trans (second)
  uint32_t seed = (uint32_t)seedp[0];
  uint32_t a0 = 0u, a1 = 2u; tf2x32(0u, seed, a0, a1);
  uint32_t b0 = 1u, b1 = 3u; tf2x32(0u, seed, b0, b1);
  const uint32_t ki0 = a0, ki1 = b0;   // k_init
  const uint32_t kt0 = a1, kt1 = b1;   // k_trans

  float vv0, vv1, ii0, ii1, ss0, ss1, icv0, icv1;
  { float2 x = *(const float2*)&v0[nb]; vv0 = x.x; vv1 = x.y; }
  { float2 x = *(const float2*)&i0[nb]; ii0 = x.x; ii1 = x.y; }
  { float2 x = *(const float2*)&ic[nb]; icv0 = x.x; icv1 = x.y; }
  // s0: uniform(k_init,(2048,)) block c -> (word0=u[c], word1=u[c+1024])
  {
    uint32_t c0 = (uint32_t)(nb < HALF_N ? nb : nb - HALF_N);
    uint32_t c1 = c0 + HALF_N;
    tf2x32(ki0, ki1, c0, c1);
    ss0 = xla_log(u01_from_bits(nb < HALF_N ? c0 : c1)) - 0.01f;
  }
  {
    int j = nb + 1;
    uint32_t c0 = (uint32_t)(j < HALF_N ? j : j - HALF_N);
    uint32_t c1 = c0 + HALF_N;
    tf2x32(ki0, ki1, c0, c1);
    ss1 = xla_log(u01_from_bits(j < HALF_N ? c0 : c1)) - 0.01f;
  }
  const float m0 = mu[0], m1 = mu[1];

  // ys[0] = y0
  {
    float* yr = ys + (size_t)nb * 3;
    ((float2*)yr)[0] = make_float2(vv0, ii0);
    ((float2*)yr)[1] = make_float2(ss0, vv1);
    ((float2*)yr)[2] = make_float2(ii1, ss1);
  }

  __shared__ uint32_t slot[4];
  if (tid < 4) slot[tid] = 0xFFFFFFFFu;
  __syncthreads();

  int nsp = 0;
  float tp = ts[0];
  float tn = ts[1];                    // pipelined: t_next for current step
  const float* srp = USE_SRES ? (sres + nb) : nullptr;
  float sr0 = 0.0f, sr1 = 0.0f;        // pipelined: reset values for current step
  if (USE_SRES) { float2 x = *(const float2*)srp; sr0 = x.x; sr1 = x.y; }
  float* yrow = ys + (size_t)N_NEUR * 3 + (size_t)nb * 3;

  for (int k = 0; k < T - 1; ++k) {
    const float dt = tn - tp;
    tp = tn;

    // ---- prefetches for NEXT step (long slack, off critical path)
    float tn_nx = ts[(k + 2 < T) ? (k + 2) : (T - 1)];
    float srn0 = 0.0f, srn1 = 0.0f;
    if (USE_SRES && (k + 1 < T - 1)) {
      float2 x = *(const float2*)(srp + N_NEUR);
      srn0 = x.x; srn1 = x.y;
      srp += N_NEUR;
    }

    // ---- event chain; wave-uniform exact shortcut for saturated regime
    float sp0, sp1;
    {
      bool f0 = (vv0 >= 16.0f), f1 = (vv1 >= 16.0f);
      if (__ballot(f0 & f1) == ~0ull) {
        sp0 = vv0; sp1 = vv1;          // softplus_xla(v)==v bit-exact for v>=16
      } else {
        sp0 = softplus_xla(vv0);
        sp1 = softplus_xla(vv1);
      }
    }
    float y1s0 = ss0 + dt * sp0;
    float y1s1 = ss1 + dt * sp1;
    const bool ev0 = (y1s0 >= 0.0f);
    const bool ev1 = (y1s1 >= 0.0f);

    // ---- wave candidate -> ds_min; tid0 resets slot[k+1]
    int lidx = ev0 ? 0 : (ev1 ? 1 : 2);
    unsigned long long bm = __ballot(lidx < 2);
    if (lane == 0 && bm) {
      int fl = __builtin_ctzll(bm);
      uint32_t cand = (uint32_t)__builtin_amdgcn_readlane(nb + lidx, fl);
      atomicMin(&slot[k & 3], cand);
    }
    if (tid == 0) slot[(k + 1) & 3] = 0xFFFFFFFFu;

    // ---- Euler v,i updates (independent of reduce; overlaps barrier)
    float dv0 = m0 * ((ii0 + icv0) - vv0);
    float dv1 = m0 * ((ii1 + icv1) - vv1);
    float y1v0 = vv0 + dt * dv0;
    float y1v1 = vv1 + dt * dv1;
    float y1i0 = ii0 + dt * ((-m1) * ii0);
    float y1i1 = ii1 + dt * ((-m1) * ii1);

    LDS_BARRIER();                     // lgkmcnt only — stores stay in flight

    uint32_t gmin = (uint32_t)__builtin_amdgcn_readfirstlane((int)slot[k & 3]);
    const bool has = (gmin != 0xFFFFFFFFu);

    // ---- w-row slice (uniform branch)
    float wv0 = 0.0f, wv1 = 0.0f;
    if (has) {
      float2 x = *(const float2*)&w[((size_t)gmin << 11) + nb];
      wv0 = x.x; wv1 = x.y;
    }

    // ---- recording (uniform-skipped after nsp reaches MS)
    if (has && nsp < MS) {
      if (tid == 0) tev[nsp] = tn;
      float* ye = yev + ((size_t)nsp * N_NEUR + nb) * 3;
      ((float2*)ye)[0] = make_float2(y1v0, y1i0);
      ((float2*)ye)[1] = make_float2(y1s0, y1v1);
      ((float2*)ye)[2] = make_float2(y1i1, y1s1);
      *(float2*)(etv + (size_t)nsp * N_NEUR + nb) =
          make_float2(ev0 ? 1.0f : 0.0f, ev1 ? 1.0f : 0.0f);
    }
    nsp += has ? 1 : 0;

    // ---- commit y2 (ev ⊆ has)
    ii0 = has ? (y1i0 + wv0) : y1i0;
    ii1 = has ? (y1i1 + wv1) : y1i1;
    vv0 = y1v0 - (ev0 ? 1.0f : 0.0f);
    vv1 = y1v1 - (ev1 ? 1.0f : 0.0f);
    if (USE_SRES) {
      ss0 = ev0 ? sr0 : y1s0;
      ss1 = ev1 ? sr1 : y1s1;
    } else {
      ss0 = y1s0; ss1 = y1s1;
      if (ev0 | ev1) {
        uint32_t f0 = 0u, f1 = (uint32_t)k;
        tf2x32(kt0, kt1, f0, f1);
        if (ev0) {
          uint32_t c0 = (uint32_t)(nb < HALF_N ? nb : nb - HALF_N);
          uint32_t c1 = c0 + HALF_N;
          tf2x32(f0, f1, c0, c1);
          ss0 = xla_log(u01_from_bits(nb < HALF_N ? c0 : c1)) - 0.01f;
        }
        if (ev1) {
          int j = nb + 1;
          uint32_t c0 = (uint32_t)(j < HALF_N ? j : j - HALF_N);
          uint32_t c1 = c0 + HALF_N;
          tf2x32(f0, f1, c0, c1);
          ss1 = xla_log(u01_from_bits(j < HALF_N ? c0 : c1)) - 0.01f;
        }
      }
    }

    // ---- store ys[k+1] = y2 (fire-and-forget; not drained at barrier)
    ((float2*)yrow)[0] = make_float2(vv0, ii0);
    ((float2*)yrow)[1] = make_float2(ss0, vv1);
    ((float2*)yrow)[2] = make_float2(ii1, ss1);
    yrow += (size_t)N_NEUR * 3;

    // rotate pipelined values
    tn = tn_nx;
    sr0 = srn0; sr1 = srn1;
  }

  if (tid == 0) nspp[0] = (float)nsp;
}

extern "C" void kernel_launch(void* const* d_in, const int* in_sizes, int n_in,
                              void* d_out, int out_size, void* d_ws, size_t ws_size,
                              hipStream_t stream) {
  const float* ts = (const float*)d_in[0];
  const float* v0 = (const float*)d_in[1];
  const float* i0 = (const float*)d_in[2];
  const float* ic = (const float*)d_in[3];
  const float* w  = (const float*)d_in[4];
  const float* mu = (const float*)d_in[5];
  const int* seed = (const int*)d_in[6];

  const int T = in_sizes[0];      // 4000
  const int N = in_sizes[1];      // 2048
  long long rem = (long long)out_size - (long long)T * N * 3 - 1;
  int MS = (int)(rem / (1 + 4 * (long long)N));
  if (MS <= 0) MS = 512;

  size_t inf_base = (size_t)T * N * 3;
  size_t inf_cnt  = (size_t)MS + (size_t)MS * N * 3;
  size_t zero_cnt = (size_t)MS * N;
  snn_init<<<dim3(512), dim3(256), 0, stream>>>((float*)d_out, inf_base, inf_cnt, zero_cnt);

  const float* sres = nullptr;
  size_t need = (size_t)(T - 1) * (size_t)N * sizeof(float);
  if (ws_size >= need) {
    snn_pre<<<dim3(T - 1), dim3(1024), 0, stream>>>(seed, (float*)d_ws);
    sres = (const float*)d_ws;
  }

  if (sres) {
    snn_sim<true><<<dim3(1), dim3(1024), 0, stream>>>(ts, v0, i0, ic, w, mu, seed,
                                                      sres, (float*)d_out, T, MS);
  } else {
    snn_sim<false><<<dim3(1), dim3(1024), 0, stream>>>(ts, v0, i0, ic, w, mu, seed,
                                                       nullptr, (float*)d_out, T, MS);
  }
}

// Round 7
// 3373.835 us; speedup vs baseline: 1.1608x; 1.1608x over previous
//
#include <hip/hip_runtime.h>
#include <stdint.h>

// ====== variant switches for XLA:CPU transcendental reconstruction ======
// (verified bit-exact in round 1 — DO NOT change the math)
#define XLA_LOG_TAIL_A 1
#define XLA_USE_FMA    0

#if XLA_USE_FMA
#define MADD(a,b,c) __builtin_fmaf((a),(b),(c))
#else
#define MADD(a,b,c) ((a)*(b)+(c))
#endif

#define N_NEUR 2048
#define HALF_N 1024
#define CKPT   125      // checkpoint/segment length for the replay pass

// raw barrier: LDS-only ordering (no vmcnt drain — loads/stores stay in flight)
#define LDS_BARRIER()                                            \
  do {                                                           \
    __asm__ __volatile__("s_waitcnt lgkmcnt(0)" ::: "memory");   \
    __builtin_amdgcn_s_barrier();                                \
    __asm__ __volatile__("" ::: "memory");                       \
  } while (0)

// ---------------- threefry2x32 (exact JAX primitive) ----------------
__device__ __forceinline__ uint32_t rotl32(uint32_t x, int r) {
  return (x << r) | (x >> (32 - r));
}

__device__ __forceinline__ void tf2x32(uint32_t k0, uint32_t k1,
                                       uint32_t& x0, uint32_t& x1) {
  const uint32_t k2 = k0 ^ k1 ^ 0x1BD11BDAu;
  x0 += k0; x1 += k1;
#define TF_R(r) { x0 += x1; x1 = rotl32(x1, r); x1 ^= x0; }
  TF_R(13) TF_R(15) TF_R(26) TF_R(6)
  x0 += k1; x1 += k2 + 1u;
  TF_R(17) TF_R(29) TF_R(16) TF_R(24)
  x0 += k2; x1 += k0 + 2u;
  TF_R(13) TF_R(15) TF_R(26) TF_R(6)
  x0 += k0; x1 += k1 + 3u;
  TF_R(17) TF_R(29) TF_R(16) TF_R(24)
  x0 += k1; x1 += k2 + 4u;
  TF_R(13) TF_R(15) TF_R(26) TF_R(6)
  x0 += k2; x1 += k0 + 5u;
#undef TF_R
}

__device__ __forceinline__ float u01_from_bits(uint32_t bits) {
#pragma clang fp contract(off)
  float f = __uint_as_float((bits >> 9) | 0x3f800000u);
  return f - 1.0f;
}

// ---------------- XLA:CPU GenerateVF32Log (Cephes, Estrin poly) ----------------
__device__ __forceinline__ float xla_log(float xin) {
#pragma clang fp contract(off)
  float t0 = fmaxf(xin, __uint_as_float(0x00800000u));
  uint32_t bits = __float_as_uint(t0);
  int em = (int)(bits >> 23) - 127;
  t0 = __uint_as_float((bits & 0x807fffffu) | 0x3f000000u);
  float e = 1.0f + (float)em;
  const bool mlt = t0 < (float)0.707106781186547524;
  float tmp1 = mlt ? t0 : 0.0f;
  t0 = t0 - 1.0f;
  e = e - (mlt ? 1.0f : 0.0f);
  t0 = t0 + tmp1;
  float x2 = t0 * t0;
  float x3 = x2 * t0;
  float y  = MADD(t0, (float)7.0376836292E-2, (float)-1.1514610310E-1);
  float ya = MADD(t0, (float)-1.2420140846E-1, (float)1.4249322787E-1);
  float yb = MADD(t0, (float)2.0000714765E-1, (float)-2.4999993993E-1);
  y  = MADD(y,  t0, (float)1.1676998740E-1);
  ya = MADD(ya, t0, (float)-1.6668057665E-1);
  yb = MADD(yb, t0, (float)3.3333331174E-1);
  y  = MADD(y, x3, ya);
  y  = MADD(y, x3, yb);
  y  = y * x3;
  float ey1 = e * (float)-2.12194440e-4;
  float hx2 = x2 * 0.5f;
  y = y + ey1;
  t0 = t0 - hx2;
  float ey2 = e * (float)0.693359375;
#if XLA_LOG_TAIL_A
  t0 = t0 + y;
  t0 = t0 + ey2;
#else
  t0 = t0 + ey2;
  t0 = t0 + y;
#endif
  if (xin == 0.0f) return -__builtin_inff();
  return t0;
}

// ---------------- XLA:CPU GenerateVF32Exp (old Cephes structure) ----------------
__device__ __forceinline__ float xla_exp(float xin) {
#pragma clang fp contract(off)
  float x = fmaxf(xin, (float)-88.3762626647949);
  x = fminf(x, (float)88.3762626647950);
  float fx = floorf(MADD(x, (float)1.44269504088896341, 0.5f));
  float tmp = (float)0.693359375 * fx;
  float z = (float)-2.12194440e-4 * fx;
  x = x - tmp;
  x = x - z;
  z = x * x;
  float y = MADD(x, (float)1.9875691500E-4, (float)1.3981999507E-3);
  y = MADD(y, x, (float)8.3334519073E-3);
  y = MADD(y, x, (float)4.1665795894E-2);
  y = MADD(y, x, (float)1.6666665459E-1);
  y = MADD(y, x, (float)5.0000001201E-1);
  y = MADD(y, z, x);
  y = 1.0f + y;
  int n = (int)fx;
  float p2n = __uint_as_float((uint32_t)(n + 127) << 23);
  return fmaxf(y * p2n, xin);
}

__device__ __forceinline__ float xla_log1p(float x) {
#pragma clang fp contract(off)
  float fl = xla_log(x + 1.0f);
  float fs = ((-0.5f * x) + 1.0f) * x;
  return (fabsf(x) < (float)1e-4) ? fs : fl;
}

// jax.nn.softplus(v) = max(v,0) + log1p(exp(-|v|))
__device__ __forceinline__ float softplus_xla(float v) {
#pragma clang fp contract(off)
  // exact shortcut: for v>=16, exp(-v)<=1.13e-7 < ulp(v)/2 -> sum rounds to v
  if (v >= 16.0f) return v;
  float a = fabsf(v);
  float ex = xla_exp(-a);
  float lp = xla_log1p(ex);
  return fmaxf(v, 0.0f) + lp;
}

// ---------------- init: tevents/yevents = +inf, event_types = 0 ----------------
__global__ void snn_init(float* __restrict__ out, size_t inf_base,
                         size_t inf_cnt, size_t zero_cnt) {
  size_t i = (size_t)blockIdx.x * blockDim.x + threadIdx.x;
  size_t stride = (size_t)gridDim.x * blockDim.x;
  size_t total = inf_cnt + zero_cnt;
  for (size_t k = i; k < total; k += stride) {
    out[inf_base + k] = (k < inf_cnt) ? __builtin_inff() : 0.0f;
  }
}

// ---------------- precompute s_reset[step][j] = log(u)-alpha into sres ---------
__global__ __launch_bounds__(1024)
void snn_pre(const int* __restrict__ seedp, float* __restrict__ sres) {
#pragma clang fp contract(off)
  const int step = blockIdx.x;       // 0..T-2
  const int t = threadIdx.x;
  uint32_t seed = (uint32_t)seedp[0];
  uint32_t a0 = 0u, a1 = 2u; tf2x32(0u, seed, a0, a1);
  uint32_t b0 = 1u, b1 = 3u; tf2x32(0u, seed, b0, b1);
  uint32_t f0 = 0u, f1 = (uint32_t)step; tf2x32(a1, b1, f0, f1);
  uint32_t d0 = (uint32_t)t, d1 = (uint32_t)(t + HALF_N);
  tf2x32(f0, f1, d0, d1);
  float srA = xla_log(u01_from_bits(d0)) - 0.01f;
  float srB = xla_log(u01_from_bits(d1)) - 0.01f;
  sres[(size_t)step * N_NEUR + t] = srA;
  sres[(size_t)step * N_NEUR + HALF_N + t] = srB;
}

// ============ PHASE A: decision chain only (1 block, 1024 thr, 2 n/t) =========
// Emits: spk[k] = (nsp_before<<16)|eidx16 (0xFFFF=none); tev/nspp; ys rows at
// k % CKPT == 0 (checkpoints for the replay pass). Pending-i (R3 semantics).
__global__ __launch_bounds__(1024, 1)
void snn_evt(const float* __restrict__ ts, const float* __restrict__ v0,
             const float* __restrict__ i0, const float* __restrict__ ic,
             const float* __restrict__ w, const float* __restrict__ mu,
             const int* __restrict__ seedp, const float* __restrict__ sres,
             uint32_t* __restrict__ spk, float* __restrict__ out, int T, int MS) {
#pragma clang fp contract(off)
  const int tid = threadIdx.x;
  const int nb = tid * 2;
  const int lane = tid & 63;

  float* ys   = out;                                     // [T][N][3]
  float* tev  = out + (size_t)T * N_NEUR * 3;            // [MS]
  float* yev  = tev + (size_t)MS;                        // [MS][N][3]
  float* etv  = yev + (size_t)MS * N_NEUR * 3;           // [MS][N]
  float* nspp = etv + (size_t)MS * N_NEUR;               // [1]

  // keys
  uint32_t seed = (uint32_t)seedp[0];
  uint32_t a0 = 0u, a1 = 2u; tf2x32(0u, seed, a0, a1);
  uint32_t b0 = 1u, b1 = 3u; tf2x32(0u, seed, b0, b1);
  const uint32_t ki0 = a0, ki1 = b0;

  float vv0, vv1, ipd0, ipd1, ss0, ss1, icv0, icv1;
  { float2 x = *(const float2*)&v0[nb]; vv0 = x.x; vv1 = x.y; }
  { float2 x = *(const float2*)&i0[nb]; ipd0 = x.x; ipd1 = x.y; }
  { float2 x = *(const float2*)&ic[nb]; icv0 = x.x; icv1 = x.y; }
  {
    uint32_t c0 = (uint32_t)(nb < HALF_N ? nb : nb - HALF_N);
    uint32_t c1 = c0 + HALF_N;
    tf2x32(ki0, ki1, c0, c1);
    ss0 = xla_log(u01_from_bits(nb < HALF_N ? c0 : c1)) - 0.01f;
  }
  {
    int j = nb + 1;
    uint32_t c0 = (uint32_t)(j < HALF_N ? j : j - HALF_N);
    uint32_t c1 = c0 + HALF_N;
    tf2x32(ki0, ki1, c0, c1);
    ss1 = xla_log(u01_from_bits(j < HALF_N ? c0 : c1)) - 0.01f;
  }
  const float m0 = mu[0], m1 = mu[1];

  __shared__ uint32_t slot[4];
  if (tid < 4) slot[tid] = 0xFFFFFFFFu;
  __syncthreads();

  int nsp = 0;
  bool hasPrev = false;
  float wvp0 = 0.0f, wvp1 = 0.0f;
  float tp = ts[0];
  float tn = ts[1];
  const float* srp = sres + nb;
  float sr0, sr1;
  { float2 x = *(const float2*)srp; sr0 = x.x; sr1 = x.y; }
  int next_ck = 0;

  for (int k = 0; k < T - 1; ++k) {
    const float dt = tn - tp;

    // prefetch next ts / sres row (consumed next iteration)
    float tn_nx = ts[(k + 2 < T) ? (k + 2) : (T - 1)];
    float srn0 = 0.0f, srn1 = 0.0f;
    if (k + 1 < T - 1) {
      float2 x = *(const float2*)(srp + N_NEUR);
      srn0 = x.x; srn1 = x.y;
      srp += N_NEUR;
    }

    // resolve committed i_k (consumes w row issued at step k-1)
    float ii0 = hasPrev ? (ipd0 + wvp0) : ipd0;
    float ii1 = hasPrev ? (ipd1 + wvp1) : ipd1;

    // checkpoint row for the replay pass (rare, uniform branch)
    if (k == next_ck) {
      float* yr = ys + ((size_t)k * N_NEUR + nb) * 3;
      ((float2*)yr)[0] = make_float2(vv0, ii0);
      ((float2*)yr)[1] = make_float2(ss0, vv1);
      ((float2*)yr)[2] = make_float2(ii1, ss1);
      next_ck += CKPT;
    }

    // event chain (expressions verbatim)
    float sp0 = softplus_xla(vv0);
    float sp1 = softplus_xla(vv1);
    float y1s0 = ss0 + dt * sp0;
    float y1s1 = ss1 + dt * sp1;
    const bool ev0 = (y1s0 >= 0.0f);
    const bool ev1 = (y1s1 >= 0.0f);

    int lidx = ev0 ? 0 : (ev1 ? 1 : 2);
    unsigned long long bm = __ballot(lidx < 2);
    if (lane == 0 && bm) {
      int fl = __builtin_ctzll(bm);
      uint32_t cand = (uint32_t)__builtin_amdgcn_readlane(nb + lidx, fl);
      atomicMin(&slot[k & 3], cand);
    }
    if (tid == 0) slot[(k + 1) & 3] = 0xFFFFFFFFu;

    // Euler updates (use resolved i_k)
    float dv0 = m0 * ((ii0 + icv0) - vv0);
    float dv1 = m0 * ((ii1 + icv1) - vv1);
    float y1v0 = vv0 + dt * dv0;
    float y1v1 = vv1 + dt * dv1;
    float y1i0 = ii0 + dt * ((-m1) * ii0);
    float y1i1 = ii1 + dt * ((-m1) * ii1);

    LDS_BARRIER();

    uint32_t gmin = (uint32_t)__builtin_amdgcn_readfirstlane((int)slot[k & 3]);
    const bool has = (gmin != 0xFFFFFFFFu);

    // issue w row load for THIS step (consumed next iteration)
    float wn0 = 0.0f, wn1 = 0.0f;
    if (has) {
      float2 x = *(const float2*)&w[((size_t)gmin << 11) + nb];
      wn0 = x.x; wn1 = x.y;
    }

    // bookkeeping (tid0)
    if (tid == 0) {
      spk[k] = ((uint32_t)nsp << 16) | (has ? (gmin & 0xFFFFu) : 0xFFFFu);
      if (has && nsp < MS) tev[nsp] = tn;
    }
    nsp += has ? 1 : 0;

    // commit (ev ⊆ has)
    vv0 = y1v0 - (ev0 ? 1.0f : 0.0f);
    vv1 = y1v1 - (ev1 ? 1.0f : 0.0f);
    ss0 = ev0 ? sr0 : y1s0;
    ss1 = ev1 ? sr1 : y1s1;
    ipd0 = y1i0; ipd1 = y1i1;
    wvp0 = wn0;  wvp1 = wn1;
    hasPrev = has;
    tp = tn; tn = tn_nx;
    sr0 = srn0; sr1 = srn1;
  }

  if (tid == 0) nspp[0] = (float)nsp;
}

// ============ PHASE B: parallel replay (32 segs x 2 halves, 1 n/t) ============
__global__ __launch_bounds__(1024, 1)
void snn_rep(const float* __restrict__ ts, const float* __restrict__ ic,
             const float* __restrict__ w, const float* __restrict__ mu,
             const float* __restrict__ sres, const uint32_t* __restrict__ spk,
             float* __restrict__ out, int T, int MS) {
#pragma clang fp contract(off)
  const int seg = blockIdx.x >> 1;
  const int gn = (blockIdx.x & 1) * 1024 + threadIdx.x;
  const int lo = seg * CKPT;
  const int end = min(lo + CKPT, T - 1);

  float* ys  = out;                                      // [T][N][3]
  float* tev = out + (size_t)T * N_NEUR * 3;
  float* yev = tev + (size_t)MS;                         // [MS][N][3]
  float* etv = yev + (size_t)MS * N_NEUR * 3;            // [MS][N]

  // start from phase-A checkpoint = committed y at step lo
  const float* y0r = ys + ((size_t)lo * N_NEUR + gn) * 3;
  float vv = y0r[0];
  float ii = y0r[1];
  float ss = y0r[2];
  const float icv = ic[gn];
  const float m0 = mu[0], m1 = mu[1];
  float tp = ts[lo];

  for (int k = lo; k < end; ++k) {
    const float tn = ts[k + 1];
    const float dt = tn - tp;
    tp = tn;
    const uint32_t pk = spk[k];

    // identical expression chain -> bit-exact state replay
    float sp  = softplus_xla(vv);
    float y1s = ss + dt * sp;
    const bool ev = (y1s >= 0.0f);
    float dv  = m0 * ((ii + icv) - vv);
    float y1v = vv + dt * dv;
    float y1i = ii + dt * ((-m1) * ii);

    const uint32_t e16 = pk & 0xFFFFu;
    const bool has = (e16 != 0xFFFFu);
    const uint32_t nsp = pk >> 16;

    float wv = 0.0f;
    if (has) wv = w[((size_t)e16 << 11) + gn];

    if (has && nsp < (uint32_t)MS) {
      float* ye = yev + ((size_t)nsp * N_NEUR + gn) * 3;
      ye[0] = y1v; ye[1] = y1i; ye[2] = y1s;
      etv[(size_t)nsp * N_NEUR + gn] = ev ? 1.0f : 0.0f;
    }

    ii = has ? (y1i + wv) : y1i;
    vv = y1v - (ev ? 1.0f : 0.0f);
    if (ev) ss = sres[(size_t)k * N_NEUR + gn]; else ss = y1s;

    float* yr = ys + ((size_t)(k + 1) * N_NEUR + gn) * 3;
    yr[0] = vv; yr[1] = ii; yr[2] = ss;
  }
}

// ============ FALLBACK: R5 single-kernel scan (if workspace too small) ========
template <bool USE_SRES>
__global__ __launch_bounds__(1024, 1)
void snn_sim(const float* __restrict__ ts, const float* __restrict__ v0,
             const float* __restrict__ i0, const float* __restrict__ ic,
             const float* __restrict__ w, const float* __restrict__ mu,
             const int* __restrict__ seedp, const float* __restrict__ sres,
             float* __restrict__ out, int T, int MS) {
#pragma clang fp contract(off)
  const int tid = threadIdx.x;
  const int nb = tid * 2;
  const int lane = tid & 63;

  float* ys   = out;
  float* tev  = out + (size_t)T * N_NEUR * 3;
  float* yev  = tev + (size_t)MS;
  float* etv  = yev + (size_t)MS * N_NEUR * 3;
  float* nspp = etv + (size_t)MS * N_NEUR;

  uint32_t seed = (uint32_t)seedp[0];
  uint32_t a0 = 0u, a1 = 2u; tf2x32(0u, seed, a0, a1);
  uint32_t b0 = 1u, b1 = 3u; tf2x32(0u, seed, b0, b1);
  const uint32_t ki0 = a0, ki1 = b0;
  const uint32_t kt0 = a1, kt1 = b1;

  float vv0, vv1, ii0, ii1, ss0, ss1, icv0, icv1;
  { float2 x = *(const float2*)&v0[nb]; vv0 = x.x; vv1 = x.y; }
  { float2 x = *(const float2*)&i0[nb]; ii0 = x.x; ii1 = x.y; }
  { float2 x = *(const float2*)&ic[nb]; icv0 = x.x; icv1 = x.y; }
  {
    uint32_t c0 = (uint32_t)(nb < HALF_N ? nb : nb - HALF_N);
    uint32_t c1 = c0 + HALF_N;
    tf2x32(ki0, ki1, c0, c1);
    ss0 = xla_log(u01_from_bits(nb < HALF_N ? c0 : c1)) - 0.01f;
  }
  {
    int j = nb + 1;
    uint32_t c0 = (uint32_t)(j < HALF_N ? j : j - HALF_N);
    uint32_t c1 = c0 + HALF_N;
    tf2x32(ki0, ki1, c0, c1);
    ss1 = xla_log(u01_from_bits(j < HALF_N ? c0 : c1)) - 0.01f;
  }
  const float m0 = mu[0], m1 = mu[1];

  {
    float* yr = ys + (size_t)nb * 3;
    ((float2*)yr)[0] = make_float2(vv0, ii0);
    ((float2*)yr)[1] = make_float2(ss0, vv1);
    ((float2*)yr)[2] = make_float2(ii1, ss1);
  }

  __shared__ uint32_t slot[4];
  if (tid < 4) slot[tid] = 0xFFFFFFFFu;
  __syncthreads();

  int nsp = 0;
  float tp = ts[0];
  const float* srp = USE_SRES ? (sres + nb) : nullptr;
  float* yrow = ys + (size_t)N_NEUR * 3 + (size_t)nb * 3;

  for (int k = 0; k < T - 1; ++k) {
    const float tn = ts[k + 1];
    const float dt = tn - tp;
    tp = tn;

    float sr0 = 0.0f, sr1 = 0.0f;
    if (USE_SRES) {
      float2 x = *(const float2*)srp;
      sr0 = x.x; sr1 = x.y;
      srp += N_NEUR;
    }

    float sp0 = softplus_xla(vv0);
    float sp1 = softplus_xla(vv1);
    float y1s0 = ss0 + dt * sp0;
    float y1s1 = ss1 + dt * sp1;
    const bool ev0 = (y1s0 >= 0.0f);
    const bool ev1 = (y1s1 >= 0.0f);

    int lidx = ev0 ? 0 : (ev1 ? 1 : 2);
    unsigned long long bm = __ballot(lidx < 2);
    if (lane == 0 && bm) {
      int fl = __builtin_ctzll(bm);
      uint32_t cand = (uint32_t)__builtin_amdgcn_readlane(nb + lidx, fl);
      atomicMin(&slot[k & 3], cand);
    }
    if (tid == 0) slot[(k + 1) & 3] = 0xFFFFFFFFu;

    float dv0 = m0 * ((ii0 + icv0) - vv0);
    float dv1 = m0 * ((ii1 + icv1) - vv1);
    float y1v0 = vv0 + dt * dv0;
    float y1v1 = vv1 + dt * dv1;
    float y1i0 = ii0 + dt * ((-m1) * ii0);
    float y1i1 = ii1 + dt * ((-m1) * ii1);

    __syncthreads();

    uint32_t gmin = (uint32_t)__builtin_amdgcn_readfirstlane((int)slot[k & 3]);
    const bool has = (gmin != 0xFFFFFFFFu);

    float wv0 = 0.0f, wv1 = 0.0f;
    if (has) {
      float2 x = *(const float2*)&w[((size_t)gmin << 11) + nb];
      wv0 = x.x; wv1 = x.y;
    }

    if (has && nsp < MS) {
      if (tid == 0) tev[nsp] = tn;
      float* ye = yev + ((size_t)nsp * N_NEUR + nb) * 3;
      ((float2*)ye)[0] = make_float2(y1v0, y1i0);
      ((float2*)ye)[1] = make_float2(y1s0, y1v1);
      ((float2*)ye)[2] = make_float2(y1i1, y1s1);
      *(float2*)(etv + (size_t)nsp * N_NEUR + nb) =
          make_float2(ev0 ? 1.0f : 0.0f, ev1 ? 1.0f : 0.0f);
    }
    nsp += has ? 1 : 0;

    ii0 = has ? (y1i0 + wv0) : y1i0;
    ii1 = has ? (y1i1 + wv1) : y1i1;
    vv0 = y1v0 - (ev0 ? 1.0f : 0.0f);
    vv1 = y1v1 - (ev1 ? 1.0f : 0.0f);
    if (USE_SRES) {
      ss0 = ev0 ? sr0 : y1s0;
      ss1 = ev1 ? sr1 : y1s1;
    } else {
      ss0 = y1s0; ss1 = y1s1;
      if (ev0 | ev1) {
        uint32_t f0 = 0u, f1 = (uint32_t)k;
        tf2x32(kt0, kt1, f0, f1);
        if (ev0) {
          uint32_t c0 = (uint32_t)(nb < HALF_N ? nb : nb - HALF_N);
          uint32_t c1 = c0 + HALF_N;
          tf2x32(f0, f1, c0, c1);
          ss0 = xla_log(u01_from_bits(nb < HALF_N ? c0 : c1)) - 0.01f;
        }
        if (ev1) {
          int j = nb + 1;
          uint32_t c0 = (uint32_t)(j < HALF_N ? j : j - HALF_N);
          uint32_t c1 = c0 + HALF_N;
          tf2x32(f0, f1, c0, c1);
          ss1 = xla_log(u01_from_bits(j < HALF_N ? c0 : c1)) - 0.01f;
        }
      }
    }

    ((float2*)yrow)[0] = make_float2(vv0, ii0);
    ((float2*)yrow)[1] = make_float2(ss0, vv1);
    ((float2*)yrow)[2] = make_float2(ii1, ss1);
    yrow += (size_t)N_NEUR * 3;
  }

  if (tid == 0) nspp[0] = (float)nsp;
}

extern "C" void kernel_launch(void* const* d_in, const int* in_sizes, int n_in,
                              void* d_out, int out_size, void* d_ws, size_t ws_size,
                              hipStream_t stream) {
  const float* ts = (const float*)d_in[0];
  const float* v0 = (const float*)d_in[1];
  const float* i0 = (const float*)d_in[2];
  const float* ic = (const float*)d_in[3];
  const float* w  = (const float*)d_in[4];
  const float* mu = (const float*)d_in[5];
  const int* seed = (const int*)d_in[6];

  const int T = in_sizes[0];      // 4000
  const int N = in_sizes[1];      // 2048
  long long rem = (long long)out_size - (long long)T * N * 3 - 1;
  int MS = (int)(rem / (1 + 4 * (long long)N));
  if (MS <= 0) MS = 512;

  size_t inf_base = (size_t)T * N * 3;
  size_t inf_cnt  = (size_t)MS + (size_t)MS * N * 3;
  size_t zero_cnt = (size_t)MS * N;
  snn_init<<<dim3(512), dim3(256), 0, stream>>>((float*)d_out, inf_base, inf_cnt, zero_cnt);

  // ws layout: [0, sres_bytes) = sres; [sres_bytes, +4*(T-1)) = spk
  size_t sres_bytes = (size_t)(T - 1) * (size_t)N * sizeof(float);
  size_t full_bytes = sres_bytes + (size_t)(T - 1) * sizeof(uint32_t);

  if (ws_size >= full_bytes) {
    float* sres = (float*)d_ws;
    uint32_t* spk = (uint32_t*)((char*)d_ws + sres_bytes);
    snn_pre<<<dim3(T - 1), dim3(1024), 0, stream>>>(seed, sres);
    snn_evt<<<dim3(1), dim3(1024), 0, stream>>>(ts, v0, i0, ic, w, mu, seed,
                                                sres, spk, (float*)d_out, T, MS);
    int nseg = (T - 1 + CKPT - 1) / CKPT;
    snn_rep<<<dim3(nseg * 2), dim3(1024), 0, stream>>>(ts, ic, w, mu, sres, spk,
                                                       (float*)d_out, T, MS);
  } else if (ws_size >= sres_bytes) {
    snn_pre<<<dim3(T - 1), dim3(1024), 0, stream>>>(seed, (float*)d_ws);
    snn_sim<true><<<dim3(1), dim3(1024), 0, stream>>>(ts, v0, i0, ic, w, mu, seed,
                                                      (const float*)d_ws,
                                                      (float*)d_out, T, MS);
  } else {
    snn_sim<false><<<dim3(1), dim3(1024), 0, stream>>>(ts, v0, i0, ic, w, mu, seed,
                                                       nullptr, (float*)d_out, T, MS);
  }
}